// Round 5
// baseline (387.014 us; speedup 1.0000x reference)
//
#include <hip/hip_runtime.h>

#define N_NODES 50000
#define N_EDGES 800000
#define D 64
#define CAP 64

typedef float vf4 __attribute__((ext_vector_type(4)));

// ---------------- K1: fused score + bucket build (batched, MLP-first) ----------------
// 16-lane group owns 16 CONTIGUOUS edges; 16 groups (256 edges) per block.
//  - src/dst for all 16 edges: ONE coalesced load each (lane l <-> edge l).
//  - all 64 atomics of a wave issue in ONE instruction upfront (lane-parallel,
//    one per edge), in flight under the whole gather+reduce phase. R4 did
//    1 atomic per group serialized on lane 0.
//  - inner loop batches 8 edges: issue 8 e-rows (nontemporal, the 204.8MB
//    sequential stream) + 8 h_src rows (random, L2-resident) into registers
//    -> 16 wave-loads in flight (~64/SIMD at 4 waves/SIMD, ~2.7x R4) -> then
//    dot + 4-step shfl_xor reduce + exp; lane j keeps w for its own edge.
//  - epilogue: ONE scatter-store instruction per wave writes all 64 slots.
// R4's k1 was latency-serialized (VALUBusy 0.6%, 3.3 TB/s, 2x byte-floor);
// this trades chain-order tweaks for raw loads-in-flight.
__global__ __launch_bounds__(256, 4) void k1_score_bucket(
    const vf4* __restrict__ h_src4, const vf4* __restrict__ e4,
    const int* __restrict__ src, const int* __restrict__ dst,
    int* __restrict__ count, int2* __restrict__ slots) {
    int t = threadIdx.x;
    int g = t >> 4, l16 = t & 15;
    int ebase = blockIdx.x * 256 + g * 16;     // this group's 16 edges
    int myedge = ebase + l16;
    int s = src[myedge];                       // coalesced across wave
    int d = dst[myedge];                       // coalesced across wave
    int pos = atomicAdd(&count[d], 1);         // 64 atomics in flight now
    float myw = 0.f;
    #pragma unroll
    for (int b = 0; b < 16; b += 8) {
        // phase 1: issue all 16 gathers for this batch
        vf4 us[8], evs[8];
        #pragma unroll
        for (int j = 0; j < 8; ++j) {
            int jj = b + j;
            int sj = __shfl(s, jj, 16);
            us[j]  = h_src4[(size_t)sj * 16 + l16];
            evs[j] = __builtin_nontemporal_load(
                &e4[(size_t)(ebase + jj) * 16 + l16]);
        }
        // phase 2: dot + 16-lane reduce + exp; lane jj keeps its edge's w
        #pragma unroll
        for (int j = 0; j < 8; ++j) {
            int jj = b + j;
            vf4 u = us[j], ev = evs[j];
            float p = u[0]*ev[0] + u[1]*ev[1] + u[2]*ev[2] + u[3]*ev[3];
            p += __shfl_xor(p, 1, 16);
            p += __shfl_xor(p, 2, 16);
            p += __shfl_xor(p, 4, 16);
            p += __shfl_xor(p, 8, 16);
            float w = __expf(p);
            myw = (jj == l16) ? w : myw;
        }
    }
    if (pos < CAP)                             // one scatter store per wave
        slots[(size_t)d * CAP + pos] = make_int2(s, __float_as_int(myw));
}

// ---------------- K23: fused aggregate + linear (unchanged) ----------------
// 16 lanes per node, 16 nodes per block (3125 blocks). Aggregation result
// goes straight into the ht LDS tile the linear epilogue consumes.
// Wl padded to stride 65: bank = (65k+o)%32 = (k+o)%32 -> conflict-free for
// both the transpose fill (lanes vary k) and the epilogue read (lanes vary o).
__global__ __launch_bounds__(256) void k23_agg_linear(
    const vf4* __restrict__ h_src4, const vf4* __restrict__ h_dst4,
    const int* __restrict__ count, const int2* __restrict__ slots,
    const float* __restrict__ W, const float* __restrict__ b,
    float* __restrict__ out) {
    __shared__ float Wl[128 * 65];                 // transposed: Wl[k*65+o]
    __shared__ __align__(16) float ht[16][132];
    int t = threadIdx.x;
    for (int i = t; i < 128 * 64; i += 256) {
        int o = i >> 7, k = i & 127;               // W is [64][128] row-major
        Wl[k * 65 + o] = W[i];
    }
    int node0 = blockIdx.x * 16;
    int n = t >> 4;
    int l16 = t & 15;
    int node = node0 + n;
    // h_dst half of ht: independent of aggregation, issue early
    *(vf4*)&ht[n][l16 * 4] = h_dst4[(size_t)node * 16 + l16];

    // ---- aggregation ----
    int cnt = count[node];
    cnt = cnt < CAP ? cnt : CAP;
    const int2* row = slots + (size_t)node * CAP;
    vf4 acc = {0.f, 0.f, 0.f, 0.f};
    float dsum = 0.f;
    int2 se = make_int2(0, 0);                     // batch-0 slot prefetch
    if (l16 < cnt) se = row[l16];
    for (int base = 0; base < cnt; base += 16) {
        int2 cur = se;
        int nxt = base + 16;
        se = make_int2(0, 0);
        if (nxt + l16 < cnt) se = row[nxt + l16];  // prefetch next batch
        // phase 1: issue all 16 gathers
        vf4 us[16];
        #pragma unroll
        for (int j = 0; j < 16; ++j) {
            int sj = __shfl(cur.x, j, 16);
            us[j] = h_src4[(size_t)sj * 16 + l16];
        }
        // phase 2: broadcast w + accumulate
        #pragma unroll
        for (int j = 0; j < 16; ++j) {
            float wj = __int_as_float(__shfl(cur.y, j, 16));
            acc += wj * us[j];
            dsum += wj;                            // same value in all 16 lanes
        }
    }
    float inv = (cnt > 0) ? 1.f / dsum : 0.f;
    acc *= inv;
    *(vf4*)&ht[n][64 + l16 * 4] = acc;
    __syncthreads();

    // ---- linear epilogue: out = [h_dst | h_sum] @ W^T + b ----
    int o = t & 63;
    int g = t >> 6;                                // nodes g*4 .. g*4+3
    float bias = b[o];
    float a0 = bias, a1 = bias, a2 = bias, a3 = bias;
    const float* h0 = &ht[g * 4 + 0][0];
    const float* h1 = &ht[g * 4 + 1][0];
    const float* h2 = &ht[g * 4 + 2][0];
    const float* h3 = &ht[g * 4 + 3][0];
    #pragma unroll
    for (int k = 0; k < 128; k += 4) {
        float w0 = Wl[(k + 0) * 65 + o];
        float w1 = Wl[(k + 1) * 65 + o];
        float w2 = Wl[(k + 2) * 65 + o];
        float w3 = Wl[(k + 3) * 65 + o];
        vf4 p0 = *(const vf4*)&h0[k];
        vf4 p1 = *(const vf4*)&h1[k];
        vf4 p2 = *(const vf4*)&h2[k];
        vf4 p3 = *(const vf4*)&h3[k];
        a0 += p0[0]*w0 + p0[1]*w1 + p0[2]*w2 + p0[3]*w3;
        a1 += p1[0]*w0 + p1[1]*w1 + p1[2]*w2 + p1[3]*w3;
        a2 += p2[0]*w0 + p2[1]*w1 + p2[2]*w2 + p2[3]*w3;
        a3 += p3[0]*w0 + p3[1]*w1 + p3[2]*w2 + p3[3]*w3;
    }
    __builtin_nontemporal_store(a0, &out[(size_t)(node0 + g * 4 + 0) * 64 + o]);
    __builtin_nontemporal_store(a1, &out[(size_t)(node0 + g * 4 + 1) * 64 + o]);
    __builtin_nontemporal_store(a2, &out[(size_t)(node0 + g * 4 + 2) * 64 + o]);
    __builtin_nontemporal_store(a3, &out[(size_t)(node0 + g * 4 + 3) * 64 + o]);
}

extern "C" void kernel_launch(void* const* d_in, const int* in_sizes, int n_in,
                              void* d_out, int out_size, void* d_ws, size_t ws_size,
                              hipStream_t stream) {
    const float* h_src = (const float*)d_in[0];
    const float* h_dst = (const float*)d_in[1];
    const float* e     = (const float*)d_in[2];
    const int*   src   = (const int*)d_in[3];
    const int*   dst   = (const int*)d_in[4];
    const float* W     = (const float*)d_in[5];
    const float* b     = (const float*)d_in[6];
    float* out = (float*)d_out;

    // workspace: count[N] | slots[N*CAP int2]
    auto align256 = [](size_t x) { return (x + 255) & ~(size_t)255; };
    char* ws = (char*)d_ws;
    int*  count = (int*)ws;
    int2* slots = (int2*)(ws + align256((size_t)N_NODES * 4));

    hipMemsetAsync(count, 0, (size_t)N_NODES * 4, stream);

    k1_score_bucket<<<N_EDGES / 256, 256, 0, stream>>>(
        (const vf4*)h_src, (const vf4*)e, src, dst, count, slots);
    k23_agg_linear<<<N_NODES / 16, 256, 0, stream>>>(
        (const vf4*)h_src, (const vf4*)h_dst, count, slots, W, b, out);
}